// Round 3
// baseline (264.764 us; speedup 1.0000x reference)
//
#include <hip/hip_runtime.h>

#define HW 224
#define NIMG 64
#define NPIX ((size_t)NIMG * HW * HW)   // 3,211,264
#define NGROUP 960                      // 64 images * 3 ch * 5 kernels
#define ACC_STRIDE 128                  // ints per group: bins 0..123, sums 124..126
#define NSUB 8                          // sub-blocks per group

// ---------------- 128-bit bitmask helpers (registers only) -----------------
struct U128 { unsigned long long lo, hi; };
__device__ __forceinline__ U128 u_or  (U128 a, U128 b){ return {a.lo|b.lo, a.hi|b.hi}; }
__device__ __forceinline__ U128 u_and (U128 a, U128 b){ return {a.lo&b.lo, a.hi&b.hi}; }
__device__ __forceinline__ U128 u_andn(U128 a, U128 b){ return {a.lo&~b.lo, a.hi&~b.hi}; }
__device__ __forceinline__ bool u_eq(U128 a, U128 b){ return a.lo==b.lo && a.hi==b.hi; }
__device__ __forceinline__ bool u_nz(U128 a){ return (a.lo | a.hi) != 0ull; }
__device__ __forceinline__ U128 u_shl(U128 a, int n){           // 1 <= n < 64
    return { a.lo << n, (a.hi << n) | (a.lo >> (64 - n)) };
}
__device__ __forceinline__ U128 u_shr(U128 a, int n){
    return { (a.lo >> n) | (a.hi << (64 - n)), a.hi >> n };
}
__device__ __forceinline__ int u_pop(U128 a){ return __popcll(a.lo) + __popcll(a.hi); }
__device__ __forceinline__ U128 u_low(U128 a){
    if (a.lo) return { a.lo & (0ull - a.lo), 0ull };
    return { 0ull, a.hi & (0ull - a.hi) };
}

// ---------------- stage 1 body, K compile-time for full unroll -------------
// S = element stride (1 = planar plane, 3 = interleaved fallback)

template<int K, int S>
__device__ __forceinline__ void stats_body(const float* __restrict__ img,
                                           int* __restrict__ acc, int sub,
                                           int hist[4][124], int* sums) {
    constexpr int KK    = K * K;
    constexpr int ROWS  = (HW + K - 1) / K;
    constexpr int P     = ROWS * ROWS;
    constexpr int PAD   = (ROWS * K - HW) / 2;
    constexpr int CHUNK = (P + NSUB - 1) / NSUB;
    const int wid = threadIdx.x >> 6;
    const int pstart = sub * CHUNK;
    const int pend   = (pstart + CHUNK < P) ? pstart + CHUNK : P;

    int t_perc = 0, t_ncomp = 0, t_marea = 0;

    for (int p = pstart + threadIdx.x; p < pend; p += 256) {
        const int pr = p / ROWS, pc = p - pr * ROWS;
        const int y0 = pr * K - PAD, x0 = pc * K - PAD;
        // center pixel always in-bounds for K in {3,5,7,9,11}
        const float cen = img[((y0 + K / 2) * HW + (x0 + K / 2)) * S];

        int ones, ncomp = 0, maxsz = 0;

        if constexpr (KK <= 64) {
            // ---- single-u64 path (K = 3,5,7) ----
            unsigned long long LCOL = 0ull, RCOL = 0ull;
#pragma unroll
            for (int i = 0; i < K; i++) { LCOL |= 1ull << (i * K); RCOL |= 1ull << (i * K + K - 1); }

            unsigned long long msk = 0ull;
#pragma unroll
            for (int i = 0; i < K; i++) {
                const int y = y0 + i;
                const bool yin = (unsigned)y < (unsigned)HW;
#pragma unroll
                for (int j = 0; j < K; j++) {
                    const int x = x0 + j;
                    const bool inb = yin && ((unsigned)x < (unsigned)HW);
                    const float v = inb ? img[(y * HW + x) * S] : 0.0f;
                    const unsigned long long bit = (fabsf(v - cen) <= (float)K) ? 1ull : 0ull;
                    msk |= bit << (i * K + j);
                }
            }
            ones = __popcll(msk);

            unsigned long long m = msk;
            while (m) {
                unsigned long long s = m & (0ull - m);
                for (;;) {
                    unsigned long long g = s | ((s & ~RCOL) << 1) | ((s & ~LCOL) >> 1)
                                             | (s << K) | (s >> K);
                    g &= m;
                    if (g == s) break;
                    s = g;
                }
                ncomp++;
                const int sz = __popcll(s);
                if (sz > maxsz) maxsz = sz;
                m &= ~s;
            }
        } else {
            // ---- U128 path (K = 9,11) ----
            U128 LCOL{0,0}, RCOL{0,0};
#pragma unroll
            for (int i = 0; i < K; i++) {
                const int cl = i * K, cr = i * K + K - 1;
                if (cl < 64) LCOL.lo |= 1ull << cl; else LCOL.hi |= 1ull << (cl - 64);
                if (cr < 64) RCOL.lo |= 1ull << cr; else RCOL.hi |= 1ull << (cr - 64);
            }

            U128 msk{0, 0};
#pragma unroll
            for (int i = 0; i < K; i++) {
                const int y = y0 + i;
                const bool yin = (unsigned)y < (unsigned)HW;
#pragma unroll
                for (int j = 0; j < K; j++) {
                    const int x = x0 + j;
                    const bool inb = yin && ((unsigned)x < (unsigned)HW);
                    const float v = inb ? img[(y * HW + x) * S] : 0.0f;
                    const unsigned long long bit = (fabsf(v - cen) <= (float)K) ? 1ull : 0ull;
                    const int c = i * K + j;
                    if (c < 64) msk.lo |= bit << c; else msk.hi |= bit << (c - 64);
                }
            }
            ones = u_pop(msk);

            U128 m = msk;
            while (u_nz(m)) {
                U128 s = u_low(m);
                for (;;) {
                    U128 g = s;
                    g = u_or(g, u_shl(u_andn(s, RCOL), 1));
                    g = u_or(g, u_shr(u_andn(s, LCOL), 1));
                    g = u_or(g, u_shl(s, K));
                    g = u_or(g, u_shr(s, K));
                    g = u_and(g, m);
                    if (u_eq(g, s)) break;
                    s = g;
                }
                ncomp++;
                const int sz = u_pop(s);
                if (sz > maxsz) maxsz = sz;
                m = u_andn(m, s);
            }
        }

        const int bgcnt = KK - ones;                 // background label 0 count
        const int marea = (bgcnt > maxsz) ? bgcnt : maxsz;

        t_ncomp += ncomp;
        t_marea += marea;
        if ((float)ones / (float)KK >= 0.59275f) t_perc++;
        atomicAdd(&hist[wid][ones], 1);
    }

    atomicAdd(&sums[0], t_perc);
    atomicAdd(&sums[1], t_ncomp);
    atomicAdd(&sums[2], t_marea);
    __syncthreads();

    // sparse global accumulation: only bins < KK matter (bin KK dropped by ref)
    for (int s = threadIdx.x; s < KK; s += 256) {
        const int v = hist[0][s] + hist[1][s] + hist[2][s] + hist[3][s];
        if (v) atomicAdd(&acc[s], v);
    }
    if (threadIdx.x < 3) atomicAdd(&acc[124 + threadIdx.x], sums[threadIdx.x]);
}

// grid.x = NGROUP * NSUB ; block = 256
template<int S>
__global__ __launch_bounds__(256) void fractal_stats(const float* __restrict__ in,
                                                     int* __restrict__ gacc) {
    const int group = blockIdx.x >> 3;
    const int sub   = blockIdx.x & 7;
    const int b     = group / 15;
    const int rem   = group % 15;
    const int ch    = rem / 5;
    const int kidx  = rem % 5;

    __shared__ int hist[4][124];                     // per-wave copies
    __shared__ int sums[3];                          // perc, ncomp, marea
    for (int i = threadIdx.x; i < 4 * 124; i += 256) ((int*)hist)[i] = 0;
    if (threadIdx.x < 3) sums[threadIdx.x] = 0;
    __syncthreads();

    const float* img = (S == 1) ? in + ((size_t)ch * NIMG + b) * HW * HW
                                : in + (size_t)b * HW * HW * 3 + ch;
    int* acc = gacc + group * ACC_STRIDE;

    switch (kidx) {                                  // block-uniform branch
        case 0: stats_body<3,  S>(img, acc, sub, hist, sums); break;
        case 1: stats_body<5,  S>(img, acc, sub, hist, sums); break;
        case 2: stats_body<7,  S>(img, acc, sub, hist, sums); break;
        case 3: stats_body<9,  S>(img, acc, sub, hist, sums); break;
        case 4: stats_body<11, S>(img, acc, sub, hist, sums); break;
    }
}

// ---------------- finalize: metrics per group ------------------------------
__global__ __launch_bounds__(256) void fractal_finalize(const int* __restrict__ gacc,
                                                        float* __restrict__ interm) {
    const int g = blockIdx.x * 256 + threadIdx.x;
    if (g >= NGROUP) return;
    const int b = g / 15, rem = g % 15, ch = rem / 5, kidx = rem % 5;
    const int k = 3 + 2 * kidx, kk = k * k;
    const int rows = (HW + k - 1) / k;
    const int P = rows * rows;
    const int* acc = gacc + g * ACC_STRIDE;

    float fd = 0.0f, m1 = 0.0f, m2 = 0.0f;
    const float Pf = (float)P;
    for (int s = 0; s < kk; s++) {
        const float prob = (float)acc[s] / Pf;
        const float n = (float)(s + 1);
        fd += prob / n;
        m1 += prob * n;
        m2 += prob * prob * n;
    }
    const float lac = (m2 - m1 * m1) / (m1 * m1);
    float* o = interm + (size_t)b * 75 + kidx * 3 + ch;
    o[0]  = (float)(acc[125] / P);   // acn  (integer floor mean)
    o[15] = (float)(acc[124] / P);   // acp
    o[30] = (float)(acc[126] / P);   // acma
    o[45] = lac;
    o[60] = fd;
}

// ---------------- NHWC -> planar, float4, + accumulator zero-fill ----------
__global__ __launch_bounds__(256) void deinterleave4(const float* __restrict__ in,
                                                     float* __restrict__ planes,
                                                     int* __restrict__ gacc) {
    const int tid = blockIdx.x * 256 + threadIdx.x;
    if (tid < NGROUP * ACC_STRIDE) gacc[tid] = 0;
    const size_t p0 = (size_t)tid * 4;
    if (p0 >= NPIX) return;
    const float4* src = (const float4*)(in + p0 * 3);
    const float4 a = src[0], bq = src[1], c = src[2];
    *(float4*)(planes + p0)            = make_float4(a.x, a.w, bq.z, c.y);
    *(float4*)(planes + NPIX + p0)     = make_float4(a.y, bq.x, bq.w, c.z);
    *(float4*)(planes + 2 * NPIX + p0) = make_float4(a.z, bq.y, c.x, c.w);
}

__global__ __launch_bounds__(256) void zero_accum(int* __restrict__ gacc) {
    const int tid = blockIdx.x * 256 + threadIdx.x;
    if (tid < NGROUP * ACC_STRIDE) gacc[tid] = 0;
}

// ---------------- stage 2: 5x5 -> 224x224 bilinear (jax half-pixel) --------
__global__ __launch_bounds__(256) void fractal_resize(const float* __restrict__ interm,
                                                      float* __restrict__ out, int total) {
    const int idx = blockIdx.x * 256 + threadIdx.x;
    if (idx >= total) return;
    const int ch = idx % 3;
    int t = idx / 3;
    const int x = t % HW; t /= HW;
    const int y = t % HW;
    const int b = t / HW;

    const float sc = 5.0f / 224.0f;
    const float uy = ((float)y + 0.5f) * sc - 0.5f;   // in (-0.5, 4.5)
    const float ux = ((float)x + 0.5f) * sc - 0.5f;

    const float fy = floorf(uy), fx = floorf(ux);
    const float wy = uy - fy,    wx = ux - fx;
    int y0 = (int)fy, x0 = (int)fx;
    int y1 = y0 + 1,  x1 = x0 + 1;
    if (y0 < 0) y0 = 0; if (x0 < 0) x0 = 0;
    if (y1 > 4) y1 = 4; if (x1 > 4) x1 = 4;

    const float* g = interm + (size_t)b * 75 + ch;
    const float v00 = g[(y0 * 5 + x0) * 3];
    const float v01 = g[(y0 * 5 + x1) * 3];
    const float v10 = g[(y1 * 5 + x0) * 3];
    const float v11 = g[(y1 * 5 + x1) * 3];

    out[idx] = (1.0f - wy) * ((1.0f - wx) * v00 + wx * v01)
             +         wy  * ((1.0f - wx) * v10 + wx * v11);
}

// ---------------- launcher -------------------------------------------------
extern "C" void kernel_launch(void* const* d_in, const int* in_sizes, int n_in,
                              void* d_out, int out_size, void* d_ws, size_t ws_size,
                              hipStream_t stream) {
    const float* in = (const float*)d_in[0];
    float* out = (float*)d_out;
    float* interm = (float*)d_ws;                       // 19,200 B
    int*   gacc   = (int*)((char*)d_ws + 19456);        // 491,520 B
    float* planes = (float*)((char*)d_ws + 512000);     // 77,070,336 B

    const size_t need = 512000 + 3 * NPIX * sizeof(float);

    if (ws_size >= need) {
        deinterleave4<<<(int)(NPIX / 4 / 256), 256, 0, stream>>>(in, planes, gacc);
        fractal_stats<1><<<NGROUP * NSUB, 256, 0, stream>>>(planes, gacc);
    } else {
        zero_accum<<<(NGROUP * ACC_STRIDE + 255) / 256, 256, 0, stream>>>(gacc);
        fractal_stats<3><<<NGROUP * NSUB, 256, 0, stream>>>(in, gacc);
    }
    fractal_finalize<<<(NGROUP + 255) / 256, 256, 0, stream>>>(gacc, interm);
    fractal_resize<<<(out_size + 255) / 256, 256, 0, stream>>>(interm, out, out_size);
}

// Round 5
// 199.645 us; speedup vs baseline: 1.3262x; 1.3262x over previous
//
#include <hip/hip_runtime.h>

#define HW 224
#define NIMG 64
#define NGROUP 960                      // 64 images * 3 ch * 5 kernels
#define LDS_F4 1914                     // 33 rows * 58 float4 = 30,624 B

// ---------------- 128-bit bitmask helpers (registers only) -----------------
struct U128 { unsigned long long lo, hi; };
__device__ __forceinline__ U128 u_or  (U128 a, U128 b){ return {a.lo|b.lo, a.hi|b.hi}; }
__device__ __forceinline__ U128 u_and (U128 a, U128 b){ return {a.lo&b.lo, a.hi&b.hi}; }
__device__ __forceinline__ U128 u_andn(U128 a, U128 b){ return {a.lo&~b.lo, a.hi&~b.hi}; }
__device__ __forceinline__ bool u_eq(U128 a, U128 b){ return a.lo==b.lo && a.hi==b.hi; }
__device__ __forceinline__ bool u_nz(U128 a){ return (a.lo | a.hi) != 0ull; }
__device__ __forceinline__ U128 u_shl(U128 a, int n){           // 1 <= n < 64
    return { a.lo << n, (a.hi << n) | (a.lo >> (64 - n)) };
}
__device__ __forceinline__ U128 u_shr(U128 a, int n){
    return { (a.lo >> n) | (a.hi << (64 - n)), a.hi >> n };
}
__device__ __forceinline__ int u_pop(U128 a){ return __popcll(a.lo) + __popcll(a.hi); }
__device__ __forceinline__ U128 u_low(U128 a){
    if (a.lo) return { a.lo & (0ull - a.lo), 0ull };
    return { 0ull, a.hi & (0ull - a.hi) };
}

// ---------------- per-group statistics, LDS-staged bands -------------------
// LDS image layout: row stride 232 floats (58 float4); image cols at
// [LPAD, LPAD+224); pad columns zeroed so patch reads need no bounds checks.
// Staging reads NHWC directly: 3 float4 = 4 pixels x 3ch, extract channel.

template<int K>
__device__ __forceinline__ void stats_group(const float* __restrict__ imgbase,
                                            int ch,
                                            float* __restrict__ o,
                                            float4* lds4, int (*hist)[124],
                                            int* sums) {
    constexpr int KK    = K * K;
    constexpr int ROWS  = (HW + K - 1) / K;          // 75,45,32,25,21
    constexpr int P     = ROWS * ROWS;
    constexpr int PAD   = (ROWS * K - HW) / 2;       // 0,0,0,0,3
    constexpr int NB    = (K==3) ? 6 : (K==5) ? 5 : (K==7) ? 4 : 3;
    constexpr int NCYC  = (ROWS + NB - 1) / NB;      // 13,9,8,9,7
    constexpr int R     = NB * K;                    // staged rows: 18,25,28,27,33
    constexpr int LPAD4 = (PAD > 0) ? 1 : 0;
    constexpr int LPAD  = 4 * LPAD4;                 // 4 for K=11, else 0
    constexpr int OFF   = LPAD - PAD;                // 1 for K=11, else 0
    constexpr int ACT   = NB * ROWS;                 // patches per cycle

    float* ldsf = (float*)lds4;
    const int tid = threadIdx.x;
    const int wid = (tid >> 6) & 1;

    for (int i = tid; i < 2 * 124; i += 256) ((int*)hist)[i] = 0;
    if (tid < 3) sums[tid] = 0;
    __syncthreads();

    int t_perc = 0, t_ncomp = 0, t_marea = 0;

    for (int s = 0; s < NCYC; s++) {
        const int gy0 = s * NB * K - PAD;

        // ---- staging: float4-coalesced directly from NHWC ----
        for (int i = tid; i < R * 56; i += 256) {
            const int r = i / 56, t4 = i - r * 56;
            const int gy = gy0 + r;
            float4 v = {0.f, 0.f, 0.f, 0.f};
            if ((unsigned)gy < (unsigned)HW) {
                // float index of pixel (gy, 4*t4) in NHWC = 3*(gy*224 + 4*t4),
                // divisible by 4 -> 16B aligned
                const float4* s4 = (const float4*)(imgbase + 3 * (gy * HW + 4 * t4));
                const float4 A = s4[0], B = s4[1], C = s4[2];
                v = (ch == 0) ? float4{A.x, A.w, B.z, C.y}
                  : (ch == 1) ? float4{A.y, B.x, B.w, C.z}
                              : float4{A.z, B.y, C.x, C.w};
            }
            lds4[r * 58 + LPAD4 + t4] = v;
        }
        // zero pad columns (2 float4 per row, disjoint from staged slots)
        for (int i = tid; i < R * 2; i += 256) {
            const int r = i >> 1, w = i & 1;
            const int slot = LPAD4 ? (w ? 57 : 0) : (56 + w);
            lds4[r * 58 + slot] = float4{0.f, 0.f, 0.f, 0.f};
        }
        __syncthreads();

        for (int pl = tid; pl < ACT; pl += 256) {
            const int bi = pl / ROWS, pc = pl - bi * ROWS;
            const int pr = s * NB + bi;
            if (pr >= ROWS) break;                   // bi nondecreasing in pl
            const int base = pc * K + OFF;           // lds col of patch x=0
            const float cen = ldsf[(bi * K + K / 2) * 232 + base + K / 2];

            int ones, ncomp = 0, maxsz = 0;

            if constexpr (KK <= 64) {
                unsigned long long LCOL = 0ull, RCOL = 0ull;
#pragma unroll
                for (int i = 0; i < K; i++) { LCOL |= 1ull << (i*K); RCOL |= 1ull << (i*K + K - 1); }
                unsigned long long msk = 0ull;
#pragma unroll
                for (int i = 0; i < K; i++) {
                    const int rb = (bi * K + i) * 232 + base;
#pragma unroll
                    for (int j = 0; j < K; j++) {
                        const float v = ldsf[rb + j];
                        msk |= (fabsf(v - cen) <= (float)K ? 1ull : 0ull) << (i * K + j);
                    }
                }
                ones = __popcll(msk);
                unsigned long long m = msk;
                while (m) {
                    unsigned long long t = m & (0ull - m);
                    for (;;) {
                        unsigned long long g = t | ((t & ~RCOL) << 1) | ((t & ~LCOL) >> 1)
                                                 | (t << K) | (t >> K);
                        g &= m;
                        if (g == t) break;
                        t = g;
                    }
                    ncomp++;
                    const int sz = __popcll(t);
                    if (sz > maxsz) maxsz = sz;
                    m &= ~t;
                }
            } else {
                U128 LCOL{0,0}, RCOL{0,0};
#pragma unroll
                for (int i = 0; i < K; i++) {
                    const int cl = i * K, cr = i * K + K - 1;
                    if (cl < 64) LCOL.lo |= 1ull << cl; else LCOL.hi |= 1ull << (cl - 64);
                    if (cr < 64) RCOL.lo |= 1ull << cr; else RCOL.hi |= 1ull << (cr - 64);
                }
                U128 msk{0, 0};
#pragma unroll
                for (int i = 0; i < K; i++) {
                    const int rb = (bi * K + i) * 232 + base;
#pragma unroll
                    for (int j = 0; j < K; j++) {
                        const float v = ldsf[rb + j];
                        const unsigned long long bit = (fabsf(v - cen) <= (float)K) ? 1ull : 0ull;
                        const int c = i * K + j;
                        if (c < 64) msk.lo |= bit << c; else msk.hi |= bit << (c - 64);
                    }
                }
                ones = u_pop(msk);
                U128 m = msk;
                while (u_nz(m)) {
                    U128 t = u_low(m);
                    for (;;) {
                        U128 g = t;
                        g = u_or(g, u_shl(u_andn(t, RCOL), 1));
                        g = u_or(g, u_shr(u_andn(t, LCOL), 1));
                        g = u_or(g, u_shl(t, K));
                        g = u_or(g, u_shr(t, K));
                        g = u_and(g, m);
                        if (u_eq(g, t)) break;
                        t = g;
                    }
                    ncomp++;
                    const int sz = u_pop(t);
                    if (sz > maxsz) maxsz = sz;
                    m = u_andn(m, t);
                }
            }

            const int bgcnt = KK - ones;             // background label 0 count
            const int marea = (bgcnt > maxsz) ? bgcnt : maxsz;
            t_ncomp += ncomp;
            t_marea += marea;
            if ((float)ones / (float)KK >= 0.59275f) t_perc++;
            atomicAdd(&hist[wid][ones], 1);
        }
        __syncthreads();
    }

    atomicAdd(&sums[0], t_perc);
    atomicAdd(&sums[1], t_ncomp);
    atomicAdd(&sums[2], t_marea);
    __syncthreads();

    if (tid < 64) {                                  // wave-parallel epilogue
        float fd = 0.f, m1 = 0.f, m2 = 0.f;
        for (int s2 = tid; s2 < KK; s2 += 64) {      // bin KK excluded (ref drops it)
            const float prob = (float)(hist[0][s2] + hist[1][s2]) / (float)P;
            const float n = (float)(s2 + 1);
            fd += prob / n;
            m1 += prob * n;
            m2 += prob * prob * n;
        }
#pragma unroll
        for (int off = 32; off; off >>= 1) {
            fd += __shfl_down(fd, off, 64);
            m1 += __shfl_down(m1, off, 64);
            m2 += __shfl_down(m2, off, 64);
        }
        if (tid == 0) {
            const float lac = (m2 - m1 * m1) / (m1 * m1);
            o[0]  = (float)(sums[1] / P);            // acn (integer floor mean)
            o[15] = (float)(sums[0] / P);            // acp
            o[30] = (float)(sums[2] / P);            // acma
            o[45] = lac;
            o[60] = fd;
        }
    }
}

// grid.x = NGROUP ; block = 256
__global__ __launch_bounds__(256) void fractal_stats(const float* __restrict__ in,
                                                     float* __restrict__ interm) {
    const int group = blockIdx.x;
    const int b = group / 15, rem = group % 15, ch = rem / 5, kidx = rem % 5;

    __shared__ float4 lds4[LDS_F4];
    __shared__ int hist[2][124];
    __shared__ int sums[3];

    const float* imgbase = in + (size_t)b * HW * HW * 3;
    float* o = interm + (size_t)b * 75 + kidx * 3 + ch;

    switch (kidx) {                                  // block-uniform branch
        case 0: stats_group<3 >(imgbase, ch, o, lds4, hist, sums); break;
        case 1: stats_group<5 >(imgbase, ch, o, lds4, hist, sums); break;
        case 2: stats_group<7 >(imgbase, ch, o, lds4, hist, sums); break;
        case 3: stats_group<9 >(imgbase, ch, o, lds4, hist, sums); break;
        case 4: stats_group<11>(imgbase, ch, o, lds4, hist, sums); break;
    }
}

// ---------------- stage 2: 5x5 -> 224x224 bilinear (jax half-pixel) --------
__global__ __launch_bounds__(256) void fractal_resize(const float* __restrict__ interm,
                                                      float* __restrict__ out, int total) {
    const int idx = blockIdx.x * 256 + threadIdx.x;
    if (idx >= total) return;
    const int ch = idx % 3;
    int t = idx / 3;
    const int x = t % HW; t /= HW;
    const int y = t % HW;
    const int b = t / HW;

    const float sc = 5.0f / 224.0f;
    const float uy = ((float)y + 0.5f) * sc - 0.5f;   // in (-0.5, 4.5)
    const float ux = ((float)x + 0.5f) * sc - 0.5f;

    const float fy = floorf(uy), fx = floorf(ux);
    const float wy = uy - fy,    wx = ux - fx;
    int y0 = (int)fy, x0 = (int)fx;
    int y1 = y0 + 1,  x1 = x0 + 1;
    if (y0 < 0) y0 = 0; if (x0 < 0) x0 = 0;
    if (y1 > 4) y1 = 4; if (x1 > 4) x1 = 4;

    const float* g = interm + (size_t)b * 75 + ch;
    const float v00 = g[(y0 * 5 + x0) * 3];
    const float v01 = g[(y0 * 5 + x1) * 3];
    const float v10 = g[(y1 * 5 + x0) * 3];
    const float v11 = g[(y1 * 5 + x1) * 3];

    out[idx] = (1.0f - wy) * ((1.0f - wx) * v00 + wx * v01)
             +         wy  * ((1.0f - wx) * v10 + wx * v11);
}

// ---------------- launcher -------------------------------------------------
extern "C" void kernel_launch(void* const* d_in, const int* in_sizes, int n_in,
                              void* d_out, int out_size, void* d_ws, size_t ws_size,
                              hipStream_t stream) {
    const float* in = (const float*)d_in[0];
    float* out = (float*)d_out;
    float* interm = (float*)d_ws;                    // 19,200 B

    fractal_stats<<<NGROUP, 256, 0, stream>>>(in, interm);
    fractal_resize<<<(out_size + 255) / 256, 256, 0, stream>>>(interm, out, out_size);
}

// Round 6
// 185.839 us; speedup vs baseline: 1.4247x; 1.0743x over previous
//
#include <hip/hip_runtime.h>

#define HW 224
#define NIMG 64
#define RB 20                           // patch-row-band height (assignment window)
#define RSTG 30                         // staged rows = RB + max halo (K-1 = 10)
#define NBAND 12                        // ceil(224/20) = 12
#define NGROUP 960                      // 64 * 3 * 5
#define ACC_STRIDE 128                  // per-group ints: bins 0..123, sums 124..126

// histogram sub-offsets per kidx (sizes KK+1: 10,26,50,82,122 -> total 290)
#define HTOT 290
__device__ __constant__ int HOFF[5] = {0, 10, 36, 86, 168};

// ---------------- 128-bit bitmask helpers (registers only) -----------------
struct U128 { unsigned long long lo, hi; };
__device__ __forceinline__ U128 u_or  (U128 a, U128 b){ return {a.lo|b.lo, a.hi|b.hi}; }
__device__ __forceinline__ U128 u_and (U128 a, U128 b){ return {a.lo&b.lo, a.hi&b.hi}; }
__device__ __forceinline__ U128 u_andn(U128 a, U128 b){ return {a.lo&~b.lo, a.hi&~b.hi}; }
__device__ __forceinline__ bool u_eq(U128 a, U128 b){ return a.lo==b.lo && a.hi==b.hi; }
__device__ __forceinline__ bool u_nz(U128 a){ return (a.lo | a.hi) != 0ull; }
__device__ __forceinline__ U128 u_shl(U128 a, int n){           // 1 <= n < 64
    return { a.lo << n, (a.hi << n) | (a.lo >> (64 - n)) };
}
__device__ __forceinline__ U128 u_shr(U128 a, int n){
    return { (a.lo >> n) | (a.hi << (64 - n)), a.hi >> n };
}
__device__ __forceinline__ int u_pop(U128 a){ return __popcll(a.lo) + __popcll(a.hi); }
__device__ __forceinline__ U128 u_low(U128 a){
    if (a.lo) return { a.lo & (0ull - a.lo), 0ull };
    return { 0ull, a.hi & (0ull - a.hi) };
}

// ---------------- per-K band compute ---------------------------------------
// LDS layout: RSTG rows, stride 232 floats; image col c at LDS col 4+c;
// LDS cols 0..3 and 228..231 zeroed; rows beyond image zeroed.
// Patch-row r (start row s=r*K-PAD) is assigned to this band iff
// max(s,0) in [y0, y0+RB). Needed rows are then within the staged window
// (top-pad rows s<0 handled via the constant-zero path, K=11 band 0 only).

template<int K>
__device__ __forceinline__ void band_k(const float* __restrict__ ldsf, int y0,
                                       int kidx, int (*hist)[HTOT], int* sums) {
    constexpr int KK   = K * K;
    constexpr int ROWS = (HW + K - 1) / K;
    constexpr int PAD  = (ROWS * K - HW) / 2;        // 0 except K=11 -> 3
    const int hoff = HOFF[kidx];
    const int wid = (threadIdx.x >> 7) & 1;

    int rlo = (y0 == 0) ? 0 : (y0 + PAD + K - 1) / K;
    int rhi = (y0 + RB + PAD + K - 1) / K;
    if (rhi > ROWS) rhi = ROWS;
    if (rhi <= rlo) return;                          // block-uniform
    const int cnt = (rhi - rlo) * ROWS;

    int t_perc = 0, t_ncomp = 0, t_marea = 0;

    for (int t = threadIdx.x; t < cnt; t += 256) {
        const int pr = rlo + t / ROWS, pc = t - (t / ROWS) * ROWS;
        const int gr0  = pr * K - PAD - y0;          // lds row of patch row 0 (>= -3)
        const int base = pc * K + (4 - PAD);         // lds col of patch col 0
        const float cen = ldsf[(gr0 + K / 2) * 232 + base + K / 2];

        int ones, ncomp = 0, maxsz = 0;

        if constexpr (KK <= 64) {
            unsigned long long LCOL = 0ull, RCOL = 0ull;
#pragma unroll
            for (int i = 0; i < K; i++) { LCOL |= 1ull << (i*K); RCOL |= 1ull << (i*K + K - 1); }
            unsigned long long msk = 0ull;
#pragma unroll
            for (int i = 0; i < K; i++) {
                const int rb2 = (gr0 + i) * 232 + base;
#pragma unroll
                for (int j = 0; j < K; j++) {
                    const float v = ldsf[rb2 + j];
                    msk |= (fabsf(v - cen) <= (float)K ? 1ull : 0ull) << (i * K + j);
                }
            }
            ones = __popcll(msk);
            unsigned long long m = msk;
            while (m) {
                unsigned long long s = m & (0ull - m);
                for (;;) {
                    unsigned long long g = s | ((s & ~RCOL) << 1) | ((s & ~LCOL) >> 1)
                                             | (s << K) | (s >> K);
                    g &= m;
                    if (g == s) break;
                    s = g;
                }
                ncomp++;
                const int sz = __popcll(s);
                if (sz > maxsz) maxsz = sz;
                m &= ~s;
            }
        } else {
            U128 LCOL{0,0}, RCOL{0,0};
#pragma unroll
            for (int i = 0; i < K; i++) {
                const int cl = i * K, cr = i * K + K - 1;
                if (cl < 64) LCOL.lo |= 1ull << cl; else LCOL.hi |= 1ull << (cl - 64);
                if (cr < 64) RCOL.lo |= 1ull << cr; else RCOL.hi |= 1ull << (cr - 64);
            }
            U128 msk{0, 0};
#pragma unroll
            for (int i = 0; i < K; i++) {
                bool padrow = false;
                if constexpr (PAD > 0) padrow = (gr0 + i < 0);   // top zero-pad rows
                if (padrow) {
                    if (cen <= (float)K) {                       // |0-cen| <= K
                        const int c0 = i * K;                    // i<3 -> bits in lo
                        msk.lo |= (((1ull << K) - 1ull) << c0);
                    }
                } else {
                    const int rb2 = (gr0 + i) * 232 + base;
#pragma unroll
                    for (int j = 0; j < K; j++) {
                        const float v = ldsf[rb2 + j];
                        const unsigned long long bit = (fabsf(v - cen) <= (float)K) ? 1ull : 0ull;
                        const int c = i * K + j;
                        if (c < 64) msk.lo |= bit << c; else msk.hi |= bit << (c - 64);
                    }
                }
            }
            ones = u_pop(msk);
            U128 m = msk;
            while (u_nz(m)) {
                U128 s = u_low(m);
                for (;;) {
                    U128 g = s;
                    g = u_or(g, u_shl(u_andn(s, RCOL), 1));
                    g = u_or(g, u_shr(u_andn(s, LCOL), 1));
                    g = u_or(g, u_shl(s, K));
                    g = u_or(g, u_shr(s, K));
                    g = u_and(g, m);
                    if (u_eq(g, s)) break;
                    s = g;
                }
                ncomp++;
                const int sz = u_pop(s);
                if (sz > maxsz) maxsz = sz;
                m = u_andn(m, s);
            }
        }

        const int bgcnt = KK - ones;                 // background label 0 count
        const int marea = (bgcnt > maxsz) ? bgcnt : maxsz;
        t_ncomp += ncomp;
        t_marea += marea;
        if ((float)ones / (float)KK >= 0.59275f) t_perc++;
        atomicAdd(&hist[wid][hoff + ones], 1);
    }

    // wave-reduce partial sums, one atomic per wave
#pragma unroll
    for (int off = 32; off; off >>= 1) {
        t_perc  += __shfl_down(t_perc,  off, 64);
        t_ncomp += __shfl_down(t_ncomp, off, 64);
        t_marea += __shfl_down(t_marea, off, 64);
    }
    if ((threadIdx.x & 63) == 0) {
        atomicAdd(&sums[kidx * 3 + 0], t_perc);
        atomicAdd(&sums[kidx * 3 + 1], t_ncomp);
        atomicAdd(&sums[kidx * 3 + 2], t_marea);
    }
}

// ---------------- stage-1 kernel: one block per (image, ch, band) ----------
// grid = 2304; XCD swizzle keeps one image's blocks on one XCD (L2 locality).

__global__ __launch_bounds__(256) void fractal_stats(const float* __restrict__ in,
                                                     int* __restrict__ gacc) {
    const int xcd  = blockIdx.x & 7;
    const int slot = blockIdx.x >> 3;                // 0..287
    const int b    = xcd + 8 * (slot / 36);          // image on XCD b%8
    const int t2   = slot % 36;
    const int ch   = t2 / 12;
    const int band = t2 % 12;
    const int y0   = band * RB;
    const int tid  = threadIdx.x;

    __shared__ float4 lds4[RSTG * 58];               // 27,840 B
    __shared__ int hist[2][HTOT];                    // 2,320 B
    __shared__ int sums[15];

    for (int i = tid; i < 2 * HTOT; i += 256) ((int*)hist)[i] = 0;
    if (tid < 15) sums[tid] = 0;

    // ---- staging: float4-coalesced from NHWC, extract block-uniform channel
    const float* imgbase = in + (size_t)b * HW * HW * 3;
    for (int i = tid; i < RSTG * 56; i += 256) {
        const int r = i / 56, t4 = i - r * 56;
        const int gy = y0 + r;
        float4 v = {0.f, 0.f, 0.f, 0.f};
        if (gy < HW) {                               // 16B aligned: 12*(gy*56+t4)*4B
            const float4* s4 = (const float4*)(imgbase + 3 * (gy * HW + 4 * t4));
            const float4 A = s4[0], B = s4[1], C = s4[2];
            if (ch == 0)      v = float4{A.x, A.w, B.z, C.y};
            else if (ch == 1) v = float4{A.y, B.x, B.w, C.z};
            else              v = float4{A.z, B.y, C.x, C.w};
        }
        lds4[r * 58 + 1 + t4] = v;
    }
    for (int i = tid; i < RSTG * 2; i += 256) {      // zero pad cols 0..3 / 228..231
        const int r = i >> 1, w = i & 1;
        lds4[r * 58 + (w ? 57 : 0)] = float4{0.f, 0.f, 0.f, 0.f};
    }
    __syncthreads();

    const float* ldsf = (const float*)lds4;
    band_k<3 >(ldsf, y0, 0, hist, sums);
    band_k<5 >(ldsf, y0, 1, hist, sums);
    band_k<7 >(ldsf, y0, 2, hist, sums);
    band_k<9 >(ldsf, y0, 3, hist, sums);
    band_k<11>(ldsf, y0, 4, hist, sums);
    __syncthreads();

    // ---- sparse global accumulation into per-group accumulators ----
    const int gbase = ((b * 3 + ch) * 5) * ACC_STRIDE;
    for (int t = tid; t < 300; t += 256) {
        if (t < 285) {                               // useful bins: 9+25+49+81+121
            int kidx, bin;
            if      (t < 9)   { kidx = 0; bin = t; }
            else if (t < 34)  { kidx = 1; bin = t - 9; }
            else if (t < 83)  { kidx = 2; bin = t - 34; }
            else if (t < 164) { kidx = 3; bin = t - 83; }
            else              { kidx = 4; bin = t - 164; }
            const int v = hist[0][HOFF[kidx] + bin] + hist[1][HOFF[kidx] + bin];
            if (v) atomicAdd(&gacc[gbase + kidx * ACC_STRIDE + bin], v);
        } else {
            const int q = t - 285, kidx = q / 3, m = q - 3 * kidx;
            const int v = sums[kidx * 3 + m];
            if (v) atomicAdd(&gacc[gbase + kidx * ACC_STRIDE + 124 + m], v);
        }
    }
}

// ---------------- zero accumulators ----------------------------------------
__global__ __launch_bounds__(256) void zero_accum(int* __restrict__ gacc) {
    const int tid = blockIdx.x * 256 + threadIdx.x;
    if (tid < NGROUP * ACC_STRIDE) gacc[tid] = 0;
}

// ---------------- finalize: metrics per group ------------------------------
__global__ __launch_bounds__(256) void fractal_finalize(const int* __restrict__ gacc,
                                                        float* __restrict__ interm) {
    const int g = blockIdx.x * 256 + threadIdx.x;
    if (g >= NGROUP) return;                         // g = (b*3+ch)*5 + kidx
    const int kidx = g % 5;
    const int t = g / 5, ch = t % 3, b = t / 3;
    const int k = 3 + 2 * kidx, kk = k * k;
    const int rows = (HW + k - 1) / k;
    const int P = rows * rows;
    const int* acc = gacc + g * ACC_STRIDE;

    float fd = 0.0f, m1 = 0.0f, m2 = 0.0f;
    const float Pf = (float)P;
    for (int s = 0; s < kk; s++) {                   // bin kk excluded (ref drops it)
        const float prob = (float)acc[s] / Pf;
        const float n = (float)(s + 1);
        fd += prob / n;
        m1 += prob * n;
        m2 += prob * prob * n;
    }
    const float lac = (m2 - m1 * m1) / (m1 * m1);
    float* o = interm + (size_t)b * 75 + kidx * 3 + ch;
    o[0]  = (float)(acc[125] / P);   // acn  (integer floor mean)
    o[15] = (float)(acc[124] / P);   // acp
    o[30] = (float)(acc[126] / P);   // acma
    o[45] = lac;
    o[60] = fd;
}

// ---------------- stage 2: 5x5 -> 224x224 bilinear (jax half-pixel) --------
__global__ __launch_bounds__(256) void fractal_resize(const float* __restrict__ interm,
                                                      float* __restrict__ out, int total) {
    const int idx = blockIdx.x * 256 + threadIdx.x;
    if (idx >= total) return;
    const int ch = idx % 3;
    int t = idx / 3;
    const int x = t % HW; t /= HW;
    const int y = t % HW;
    const int b = t / HW;

    const float sc = 5.0f / 224.0f;
    const float uy = ((float)y + 0.5f) * sc - 0.5f;   // in (-0.5, 4.5)
    const float ux = ((float)x + 0.5f) * sc - 0.5f;

    const float fy = floorf(uy), fx = floorf(ux);
    const float wy = uy - fy,    wx = ux - fx;
    int y0 = (int)fy, x0 = (int)fx;
    int y1 = y0 + 1,  x1 = x0 + 1;
    if (y0 < 0) y0 = 0; if (x0 < 0) x0 = 0;
    if (y1 > 4) y1 = 4; if (x1 > 4) x1 = 4;

    const float* g = interm + (size_t)b * 75 + ch;
    const float v00 = g[(y0 * 5 + x0) * 3];
    const float v01 = g[(y0 * 5 + x1) * 3];
    const float v10 = g[(y1 * 5 + x0) * 3];
    const float v11 = g[(y1 * 5 + x1) * 3];

    out[idx] = (1.0f - wy) * ((1.0f - wx) * v00 + wx * v01)
             +         wy  * ((1.0f - wx) * v10 + wx * v11);
}

// ---------------- launcher -------------------------------------------------
extern "C" void kernel_launch(void* const* d_in, const int* in_sizes, int n_in,
                              void* d_out, int out_size, void* d_ws, size_t ws_size,
                              hipStream_t stream) {
    const float* in = (const float*)d_in[0];
    float* out = (float*)d_out;
    float* interm = (float*)d_ws;                    // 19,200 B
    int*   gacc   = (int*)((char*)d_ws + 19456);     // 491,520 B

    zero_accum<<<(NGROUP * ACC_STRIDE + 255) / 256, 256, 0, stream>>>(gacc);
    fractal_stats<<<NIMG * 3 * NBAND, 256, 0, stream>>>(in, gacc);
    fractal_finalize<<<(NGROUP + 255) / 256, 256, 0, stream>>>(gacc, interm);
    fractal_resize<<<(out_size + 255) / 256, 256, 0, stream>>>(interm, out, out_size);
}